// Round 3
// baseline (341.440 us; speedup 1.0000x reference)
//
#include <hip/hip_runtime.h>
#include <hip/hip_bf16.h>

#define S_LEN 4096
#define DMODEL 1024
#define NHEAD 16
#define DK 64

typedef __hip_bfloat16 bf16;
typedef __attribute__((ext_vector_type(8))) __bf16 bf16x8;
typedef __attribute__((ext_vector_type(4))) float f32x4;

__device__ __forceinline__ f32x4 mfma16(bf16x8 a, bf16x8 b, f32x4 c) {
    return __builtin_amdgcn_mfma_f32_16x16x32_bf16(a, b, c, 0, 0, 0);
}

// async global->LDS, 16B per lane. LDS dest is wave-uniform base + lane*16.
__device__ __forceinline__ void async16(const bf16* g, bf16* l) {
    __builtin_amdgcn_global_load_lds(
        (const __attribute__((address_space(1))) unsigned int*)g,
        (__attribute__((address_space(3))) unsigned int*)l, 16, 0, 0);
}

__device__ __forceinline__ bf16x8 cvt8(float4 a, float4 b) {
    bf16x8 r;
    r[0] = (__bf16)a.x; r[1] = (__bf16)a.y; r[2] = (__bf16)a.z; r[3] = (__bf16)a.w;
    r[4] = (__bf16)b.x; r[5] = (__bf16)b.y; r[6] = (__bf16)b.z; r[7] = (__bf16)b.w;
    return r;
}

// C[M=4096][N=1024] = A[M][K=1024] * B[N][K]^T, 128x128 tile, bf16 MFMA compute.
// MODE 0 (QKV): A = f32 global (convert-stage), out = bf16 head-major
//               C[(n>>6)*S + m][n&63] with scale folded in.
// MODE 1 (OUT): A = bf16 ws (global_load_lds), out = f32 row-major C[m][n].
// B is always f32 weights (convert-stage).
template <int MODE>
__device__ __forceinline__ void gemm_body(const void* Ap, const float* B,
                                          void* Cp, float scale) {
    constexpr int K = DMODEL;
    __shared__ bf16 As[128 * 32];
    __shared__ bf16 Bs[128 * 32];

    const int t = threadIdx.x;
    const int lane = t & 63;
    const int l15 = lane & 15, lhi = lane >> 4;
    const int wave = t >> 6;
    const int wm = wave >> 1, wn = wave & 1;
    const int bm = blockIdx.y, bn = blockIdx.x;

    const int srow = t >> 2, scol = (t & 3) * 8;  // staging: 64 rows/half, 8 elems/thread

    const float* gB = B + (size_t)(bn * 128 + srow) * K + scol;
    const float* gAf = (const float*)Ap + (size_t)(bm * 128 + srow) * K + scol;
    const bf16* gAb = (const bf16*)Ap + (size_t)(bm * 128 + srow) * K + scol;

    f32x4 acc[4][4];
#pragma unroll
    for (int i = 0; i < 4; ++i)
#pragma unroll
        for (int j = 0; j < 4; ++j) acc[i][j] = (f32x4){0.f, 0.f, 0.f, 0.f};

    for (int kt = 0; kt < K / 32; ++kt) {
        if (MODE == 0) {
            float4 a0 = *(const float4*)(gAf + kt * 32);
            float4 a1 = *(const float4*)(gAf + kt * 32 + 4);
            *(bf16x8*)&As[srow * 32 + scol] = cvt8(a0, a1);
            float4 a2 = *(const float4*)(gAf + kt * 32 + 64 * K);
            float4 a3 = *(const float4*)(gAf + kt * 32 + 64 * K + 4);
            *(bf16x8*)&As[2048 + srow * 32 + scol] = cvt8(a2, a3);
        } else {
            async16(gAb + kt * 32,          (bf16*)As + t * 8);
            async16(gAb + kt * 32 + 64 * K, (bf16*)As + 2048 + t * 8);
        }
        {
            float4 b0 = *(const float4*)(gB + kt * 32);
            float4 b1 = *(const float4*)(gB + kt * 32 + 4);
            *(bf16x8*)&Bs[srow * 32 + scol] = cvt8(b0, b1);
            float4 b2 = *(const float4*)(gB + kt * 32 + 64 * K);
            float4 b3 = *(const float4*)(gB + kt * 32 + 64 * K + 4);
            *(bf16x8*)&Bs[2048 + srow * 32 + scol] = cvt8(b2, b3);
        }
        __syncthreads();

        bf16x8 af[4], bv[4];
#pragma unroll
        for (int mt = 0; mt < 4; ++mt)
            af[mt] = *(const bf16x8*)&As[(wm * 64 + mt * 16 + l15) * 32 + lhi * 8];
#pragma unroll
        for (int nt = 0; nt < 4; ++nt)
            bv[nt] = *(const bf16x8*)&Bs[(wn * 64 + nt * 16 + l15) * 32 + lhi * 8];
#pragma unroll
        for (int mt = 0; mt < 4; ++mt)
#pragma unroll
            for (int nt = 0; nt < 4; ++nt)
                acc[mt][nt] = mfma16(af[mt], bv[nt], acc[mt][nt]);
        __syncthreads();
    }

#pragma unroll
    for (int mt = 0; mt < 4; ++mt)
#pragma unroll
        for (int nt = 0; nt < 4; ++nt)
#pragma unroll
            for (int r = 0; r < 4; ++r) {
                int m = bm * 128 + wm * 64 + mt * 16 + lhi * 4 + r;
                int n = bn * 128 + wn * 64 + nt * 16 + l15;
                float v = acc[mt][nt][r] * scale;
                if (MODE == 0)
                    ((bf16*)Cp)[((size_t)(n >> 6) * S_LEN + m) * DK + (n & 63)] =
                        __float2bfloat16(v);
                else
                    ((float*)Cp)[(size_t)m * DMODEL + n] = v;
            }
}

__global__ __launch_bounds__(256) void qkv_proj(const float* __restrict__ x,
                                                const float* __restrict__ Wq,
                                                const float* __restrict__ Wk,
                                                const float* __restrict__ Wv,
                                                bf16* __restrict__ q,
                                                bf16* __restrict__ k,
                                                bf16* __restrict__ v) {
    const int z = blockIdx.z;
    const float* B = (z == 0) ? Wq : (z == 1 ? Wk : Wv);
    bf16* out = (z == 0) ? q : (z == 1 ? k : v);
    // fold softmax scale (1/sqrt(64)) and log2(e) into stored Q
    float scale = (z == 0) ? 0.18033688011112042f : 1.0f;
    gemm_body<0>(x, B, out, scale);
}

__global__ __launch_bounds__(256) void out_proj(const bf16* __restrict__ A,
                                                const float* __restrict__ Wo,
                                                float* __restrict__ C) {
    gemm_body<1>(A, Wo, C, 1.0f);
}

// Flash attention, causal. Block: 1 head x 64 q-rows, 4 waves x 16 rows.
// q/k/v head-major [H][S][64] bf16; output attn [S][D] bf16 (heads re-interleaved).
__global__ __launch_bounds__(256) void attn_kernel(const bf16* __restrict__ Q,
                                                   const bf16* __restrict__ Kg,
                                                   const bf16* __restrict__ Vg,
                                                   bf16* __restrict__ O) {
    __shared__ bf16 Ks[64][72];       // +8 pad: rows stay 16B-aligned
    __shared__ bf16 Vt[64][72];       // V transposed: Vt[d][kv]
    __shared__ bf16 Ps[4][16][72];    // per-wave P round-trip (C-layout -> A-layout)

    const int h = blockIdx.y;
    const int qb = blockIdx.x;
    const int t = threadIdx.x;
    const int lane = t & 63;
    const int l15 = lane & 15, lhi = lane >> 4;
    const int wave = t >> 6;
    const int q0w = qb * 64 + wave * 16;

    const bf16* qh = Q + (size_t)h * S_LEN * DK;
    const bf16* kh = Kg + (size_t)h * S_LEN * DK;
    const bf16* vh = Vg + (size_t)h * S_LEN * DK;

    // Q A-fragments: row = l15 (q row), k = lhi*8 + j, chunks k0=0,32 (scale pre-folded)
    bf16x8 qf0 = *(const bf16x8*)&qh[(size_t)(q0w + l15) * DK + lhi * 8];
    bf16x8 qf1 = *(const bf16x8*)&qh[(size_t)(q0w + l15) * DK + 32 + lhi * 8];

    float m_r[4], l_r[4];
    f32x4 oacc[4];
#pragma unroll
    for (int r = 0; r < 4; ++r) { m_r[r] = -3.0e38f; l_r[r] = 0.f; }
#pragma unroll
    for (int d = 0; d < 4; ++d) oacc[d] = (f32x4){0.f, 0.f, 0.f, 0.f};

    const int srow = t >> 2, schk = t & 3;  // K staging: 64 rows, 4 threads/row, 32B each
    const int vkv = t & 63, vdc = t >> 6;   // V staging: kv row, 16-d chunk

    for (int kt = 0; kt <= qb; ++kt) {
        const int k0 = kt * 64;
        __syncthreads();  // previous iter's LDS reads done before restage
        *(uint4*)&Ks[srow][schk * 16] =
            *(const uint4*)&kh[(size_t)(k0 + srow) * DK + schk * 16];
        *(uint4*)&Ks[srow][schk * 16 + 8] =
            *(const uint4*)&kh[(size_t)(k0 + srow) * DK + schk * 16 + 8];
        {
            uint4 a = *(const uint4*)&vh[(size_t)(k0 + vkv) * DK + vdc * 16];
            uint4 b = *(const uint4*)&vh[(size_t)(k0 + vkv) * DK + vdc * 16 + 8];
            const bf16* pa = (const bf16*)&a;
            const bf16* pb = (const bf16*)&b;
#pragma unroll
            for (int i = 0; i < 8; ++i) Vt[vdc * 16 + i][vkv] = pa[i];
#pragma unroll
            for (int i = 0; i < 8; ++i) Vt[vdc * 16 + 8 + i][vkv] = pb[i];
        }
        __syncthreads();

        // QK^T: S[16q][64k], B-frag from Ks rows (col = k index = nt*16+l15)
        f32x4 sc[4];
#pragma unroll
        for (int nt = 0; nt < 4; ++nt) {
            bf16x8 kf0 = *(const bf16x8*)&Ks[nt * 16 + l15][lhi * 8];
            bf16x8 kf1 = *(const bf16x8*)&Ks[nt * 16 + l15][32 + lhi * 8];
            f32x4 c = (f32x4){0.f, 0.f, 0.f, 0.f};
            c = mfma16(qf0, kf0, c);
            c = mfma16(qf1, kf1, c);
            sc[nt] = c;
        }

        if (k0 + 63 > q0w) {  // diagonal-range tile: elementwise causal mask
#pragma unroll
            for (int nt = 0; nt < 4; ++nt)
#pragma unroll
                for (int r = 0; r < 4; ++r) {
                    int kg = k0 + nt * 16 + l15;
                    int qg = q0w + lhi * 4 + r;
                    if (kg > qg) sc[nt][r] = -3.0e38f;
                }
        }

        // row max over 64 cols: 4 frags elementwise + shfl over the 16-lane group
        float tm[4], rs[4], alpha[4];
#pragma unroll
        for (int r = 0; r < 4; ++r)
            tm[r] = fmaxf(fmaxf(sc[0][r], sc[1][r]), fmaxf(sc[2][r], sc[3][r]));
#pragma unroll
        for (int off = 8; off >= 1; off >>= 1)
#pragma unroll
            for (int r = 0; r < 4; ++r)
                tm[r] = fmaxf(tm[r], __shfl_xor(tm[r], off));

#pragma unroll
        for (int r = 0; r < 4; ++r) {
            float mn = fmaxf(m_r[r], tm[r]);
            alpha[r] = exp2f(m_r[r] - mn);
            m_r[r] = mn;
            rs[r] = 0.f;
        }
#pragma unroll
        for (int nt = 0; nt < 4; ++nt)
#pragma unroll
            for (int r = 0; r < 4; ++r) {
                float p = exp2f(sc[nt][r] - m_r[r]);  // log2e pre-folded into Q
                sc[nt][r] = p;
                rs[r] += p;
            }
#pragma unroll
        for (int off = 8; off >= 1; off >>= 1)
#pragma unroll
            for (int r = 0; r < 4; ++r) rs[r] += __shfl_xor(rs[r], off);
#pragma unroll
        for (int r = 0; r < 4; ++r) l_r[r] = l_r[r] * alpha[r] + rs[r];

        // P: C-layout (row=lhi*4+r, col=nt*16+l15) -> LDS -> A-layout reads
#pragma unroll
        for (int nt = 0; nt < 4; ++nt)
#pragma unroll
            for (int r = 0; r < 4; ++r)
                Ps[wave][lhi * 4 + r][nt * 16 + l15] = __float2bfloat16(sc[nt][r]);

#pragma unroll
        for (int d = 0; d < 4; ++d)
#pragma unroll
            for (int r = 0; r < 4; ++r) oacc[d][r] *= alpha[r];

#pragma unroll
        for (int kc = 0; kc < 2; ++kc) {
            bf16x8 pf = *(const bf16x8*)&Ps[wave][l15][kc * 32 + lhi * 8];
#pragma unroll
            for (int d = 0; d < 4; ++d) {
                bf16x8 vf = *(const bf16x8*)&Vt[d * 16 + l15][kc * 32 + lhi * 8];
                oacc[d] = mfma16(pf, vf, oacc[d]);
            }
        }
    }

#pragma unroll
    for (int d = 0; d < 4; ++d)
#pragma unroll
        for (int r = 0; r < 4; ++r) {
            int qg = q0w + lhi * 4 + r;
            int dg = d * 16 + l15;
            float val = oacc[d][r] / l_r[r];
            O[(size_t)qg * DMODEL + h * DK + dg] = __float2bfloat16(val);
        }
}

extern "C" void kernel_launch(void* const* d_in, const int* in_sizes, int n_in,
                              void* d_out, int out_size, void* d_ws, size_t ws_size,
                              hipStream_t stream) {
    const float* x  = (const float*)d_in[0];
    const float* Wq = (const float*)d_in[1];
    const float* Wk = (const float*)d_in[2];
    const float* Wv = (const float*)d_in[3];
    const float* Wo = (const float*)d_in[4];
    float* out = (float*)d_out;

    bf16* q_ws = (bf16*)d_ws;                    // [H][S][64] bf16
    bf16* k_ws = q_ws + (size_t)S_LEN * DMODEL;  // [H][S][64] bf16
    bf16* v_ws = k_ws + (size_t)S_LEN * DMODEL;  // [H][S][64] bf16
    bf16* a_ws = v_ws + (size_t)S_LEN * DMODEL;  // [S][D] bf16

    dim3 gq(DMODEL / 128, S_LEN / 128, 3);
    qkv_proj<<<gq, 256, 0, stream>>>(x, Wq, Wk, Wv, q_ws, k_ws, v_ws);
    dim3 ga(S_LEN / 64, NHEAD);
    attn_kernel<<<ga, 256, 0, stream>>>(q_ws, k_ws, v_ws, a_ws);
    dim3 go(DMODEL / 128, S_LEN / 128);
    out_proj<<<go, 256, 0, stream>>>(a_ws, Wo, out);
}

// Round 4
// 281.783 us; speedup vs baseline: 1.2117x; 1.2117x over previous
//
#include <hip/hip_runtime.h>
#include <hip/hip_bf16.h>

#define S_LEN 4096
#define DMODEL 1024
#define NHEAD 16
#define DK 64

typedef __hip_bfloat16 bf16;
typedef __attribute__((ext_vector_type(8))) __bf16 bf16x8;
typedef __attribute__((ext_vector_type(4))) float f32x4;

__device__ __forceinline__ f32x4 mfma16(bf16x8 a, bf16x8 b, f32x4 c) {
    return __builtin_amdgcn_mfma_f32_16x16x32_bf16(a, b, c, 0, 0, 0);
}

// async global->LDS, 16B per lane. LDS dest is wave-uniform base + lane*16.
__device__ __forceinline__ void async16(const bf16* g, bf16* l) {
    __builtin_amdgcn_global_load_lds(
        (const __attribute__((address_space(1))) unsigned int*)g,
        (__attribute__((address_space(3))) unsigned int*)l, 16, 0, 0);
}

__device__ __forceinline__ bf16x8 cvt8(float4 a, float4 b) {
    bf16x8 r;
    r[0] = (__bf16)a.x; r[1] = (__bf16)a.y; r[2] = (__bf16)a.z; r[3] = (__bf16)a.w;
    r[4] = (__bf16)b.x; r[5] = (__bf16)b.y; r[6] = (__bf16)b.z; r[7] = (__bf16)b.w;
    return r;
}

// XOR-swizzled index into a [rows][64] bf16 tile (128B rows): 16B slot ^ (row&7).
// Conflict-free for b128 reads where lanes walk rows (in-order lane octets hit
// 8 distinct 16B slots). 'col' is the bf16 column 0..63.
__device__ __forceinline__ int swze(int row, int col) {
    return row * 64 + ((((col >> 3) ^ (row & 7)) << 3) | (col & 7));
}
__device__ __forceinline__ int swz8(int row, int col8) {  // col8 = col>>3
    return row * 64 + (((col8 ^ (row & 7)) << 3));
}

// C[M=4096][N=1024] = A[M][K=1024] * B[N][K]^T, 128x128 tile, bf16 MFMA compute.
// MODE 0 (QKV): A = f32 global (convert-stage), out = bf16 head-major
// MODE 1 (OUT): A = bf16 ws (global_load_lds), out = f32 row-major
template <int MODE>
__device__ __forceinline__ void gemm_body(const void* Ap, const float* B,
                                          void* Cp, float scale) {
    constexpr int K = DMODEL;
    __shared__ bf16 As[128 * 32];
    __shared__ bf16 Bs[128 * 32];

    const int t = threadIdx.x;
    const int lane = t & 63;
    const int l15 = lane & 15, lhi = lane >> 4;
    const int wave = t >> 6;
    const int wm = wave >> 1, wn = wave & 1;
    const int bm = blockIdx.y, bn = blockIdx.x;

    const int srow = t >> 2, scol = (t & 3) * 8;

    const float* gB = B + (size_t)(bn * 128 + srow) * K + scol;
    const float* gAf = (const float*)Ap + (size_t)(bm * 128 + srow) * K + scol;
    const bf16* gAb = (const bf16*)Ap + (size_t)(bm * 128 + srow) * K + scol;

    f32x4 acc[4][4];
#pragma unroll
    for (int i = 0; i < 4; ++i)
#pragma unroll
        for (int j = 0; j < 4; ++j) acc[i][j] = (f32x4){0.f, 0.f, 0.f, 0.f};

    for (int kt = 0; kt < K / 32; ++kt) {
        if (MODE == 0) {
            float4 a0 = *(const float4*)(gAf + kt * 32);
            float4 a1 = *(const float4*)(gAf + kt * 32 + 4);
            *(bf16x8*)&As[srow * 32 + scol] = cvt8(a0, a1);
            float4 a2 = *(const float4*)(gAf + kt * 32 + 64 * K);
            float4 a3 = *(const float4*)(gAf + kt * 32 + 64 * K + 4);
            *(bf16x8*)&As[2048 + srow * 32 + scol] = cvt8(a2, a3);
        } else {
            async16(gAb + kt * 32,          (bf16*)As + t * 8);
            async16(gAb + kt * 32 + 64 * K, (bf16*)As + 2048 + t * 8);
        }
        {
            float4 b0 = *(const float4*)(gB + kt * 32);
            float4 b1 = *(const float4*)(gB + kt * 32 + 4);
            *(bf16x8*)&Bs[srow * 32 + scol] = cvt8(b0, b1);
            float4 b2 = *(const float4*)(gB + kt * 32 + 64 * K);
            float4 b3 = *(const float4*)(gB + kt * 32 + 64 * K + 4);
            *(bf16x8*)&Bs[2048 + srow * 32 + scol] = cvt8(b2, b3);
        }
        __syncthreads();

        bf16x8 af[4], bv[4];
#pragma unroll
        for (int mt = 0; mt < 4; ++mt)
            af[mt] = *(const bf16x8*)&As[(wm * 64 + mt * 16 + l15) * 32 + lhi * 8];
#pragma unroll
        for (int nt = 0; nt < 4; ++nt)
            bv[nt] = *(const bf16x8*)&Bs[(wn * 64 + nt * 16 + l15) * 32 + lhi * 8];
#pragma unroll
        for (int mt = 0; mt < 4; ++mt)
#pragma unroll
            for (int nt = 0; nt < 4; ++nt)
                acc[mt][nt] = mfma16(af[mt], bv[nt], acc[mt][nt]);
        __syncthreads();
    }

#pragma unroll
    for (int mt = 0; mt < 4; ++mt)
#pragma unroll
        for (int nt = 0; nt < 4; ++nt)
#pragma unroll
            for (int r = 0; r < 4; ++r) {
                int m = bm * 128 + wm * 64 + mt * 16 + lhi * 4 + r;
                int n = bn * 128 + wn * 64 + nt * 16 + l15;
                float v = acc[mt][nt][r] * scale;
                if (MODE == 0)
                    ((bf16*)Cp)[((size_t)(n >> 6) * S_LEN + m) * DK + (n & 63)] =
                        __float2bfloat16(v);
                else
                    ((float*)Cp)[(size_t)m * DMODEL + n] = v;
            }
}

__global__ __launch_bounds__(256) void qkv_proj(const float* __restrict__ x,
                                                const float* __restrict__ Wq,
                                                const float* __restrict__ Wk,
                                                const float* __restrict__ Wv,
                                                bf16* __restrict__ q,
                                                bf16* __restrict__ k,
                                                bf16* __restrict__ v) {
    const int z = blockIdx.z;
    const float* B = (z == 0) ? Wq : (z == 1 ? Wk : Wv);
    bf16* out = (z == 0) ? q : (z == 1 ? k : v);
    float scale = (z == 0) ? 0.18033688011112042f : 1.0f;  // (1/sqrt(64))*log2(e)
    gemm_body<0>(x, B, out, scale);
}

__global__ __launch_bounds__(256) void out_proj(const bf16* __restrict__ A,
                                                const float* __restrict__ Wo,
                                                float* __restrict__ C) {
    gemm_body<1>(A, Wo, C, 1.0f);
}

// Flash attention, causal. Block: 1 head x 128 q-rows, 4 waves x 32 rows each.
// KV tile = 64. Double-buffered LDS, one barrier per iter, T14 load/write split.
__global__ __launch_bounds__(256) void attn_kernel(const bf16* __restrict__ Q,
                                                   const bf16* __restrict__ Kg,
                                                   const bf16* __restrict__ Vg,
                                                   bf16* __restrict__ O) {
    __shared__ bf16 Ks[2][64 * 64];   // swizzled [kv][d]
    __shared__ bf16 Vt[2][64 * 64];   // swizzled [d][kv]
    __shared__ bf16 Ps[4][32 * 64];   // per-wave swizzled [qrow][kv]

    const int h = blockIdx.x;
    const int qb = 31 - blockIdx.y;   // long blocks (high qb) dispatch first
    const int t = threadIdx.x;
    const int lane = t & 63;
    const int l15 = lane & 15, lhi = lane >> 4;
    const int wave = t >> 6;
    const int q0w = qb * 128 + wave * 32;

    const bf16* qh = Q + (size_t)h * S_LEN * DK;
    const bf16* kh = Kg + (size_t)h * S_LEN * DK;
    const bf16* vh = Vg + (size_t)h * S_LEN * DK;

    // Q A-fragments: [mt][chunk]: row q0w+mt*16+l15, k = chunk*32+lhi*8 (scale folded)
    bf16x8 qf[2][2];
#pragma unroll
    for (int mt = 0; mt < 2; ++mt)
#pragma unroll
        for (int c = 0; c < 2; ++c)
            qf[mt][c] = *(const bf16x8*)&qh[(size_t)(q0w + mt * 16 + l15) * DK +
                                            c * 32 + lhi * 8];

    float m_r[2][4], l_r[2][4];
    f32x4 oacc[2][4];
#pragma unroll
    for (int mt = 0; mt < 2; ++mt) {
#pragma unroll
        for (int r = 0; r < 4; ++r) { m_r[mt][r] = -3.0e38f; l_r[mt][r] = 0.f; }
#pragma unroll
        for (int d = 0; d < 4; ++d) oacc[mt][d] = (f32x4){0.f, 0.f, 0.f, 0.f};
    }

    const int srow = t >> 2, sc0 = (t & 3) * 16;  // K staging: row, col base
    const int vkv = lane;                          // V staging: wave owns d-chunk wave*16

    uint4 kr0, kr1, vr0, vr1;  // staged tile registers (T14 split)
    const int NT = 2 * qb + 2;

    auto load_regs = [&](int kt) {
        const int k0 = kt * 64;
        kr0 = *(const uint4*)&kh[(size_t)(k0 + srow) * DK + sc0];
        kr1 = *(const uint4*)&kh[(size_t)(k0 + srow) * DK + sc0 + 8];
        vr0 = *(const uint4*)&vh[(size_t)(k0 + vkv) * DK + wave * 16];
        vr1 = *(const uint4*)&vh[(size_t)(k0 + vkv) * DK + wave * 16 + 8];
    };
    auto write_lds = [&](int buf) {
        *(uint4*)&Ks[buf][swz8(srow, (sc0 >> 3))] = kr0;
        *(uint4*)&Ks[buf][swz8(srow, (sc0 >> 3) + 1)] = kr1;
        const bf16* pa = (const bf16*)&vr0;
        const bf16* pb = (const bf16*)&vr1;
#pragma unroll
        for (int i = 0; i < 8; ++i) Vt[buf][swze(wave * 16 + i, vkv)] = pa[i];
#pragma unroll
        for (int i = 0; i < 8; ++i) Vt[buf][swze(wave * 16 + 8 + i, vkv)] = pb[i];
    };

    load_regs(0);
    write_lds(0);
    __syncthreads();

    for (int kt = 0; kt < NT; ++kt) {
        const int k0 = kt * 64;
        const int p = kt & 1;
        if (kt + 1 < NT) load_regs(kt + 1);  // global loads in flight under compute

        if (k0 <= q0w + 31) {  // skip fully-masked tiles (still stage + barrier)
            // ---- QK^T ----
            f32x4 s[2][4];
#pragma unroll
            for (int nt = 0; nt < 4; ++nt) {
                const int kr = nt * 16 + l15;
                bf16x8 kf0 = *(const bf16x8*)&Ks[p][swz8(kr, lhi)];
                bf16x8 kf1 = *(const bf16x8*)&Ks[p][swz8(kr, 4 + lhi)];
#pragma unroll
                for (int mt = 0; mt < 2; ++mt) {
                    f32x4 c = (f32x4){0.f, 0.f, 0.f, 0.f};
                    c = mfma16(qf[mt][0], kf0, c);
                    c = mfma16(qf[mt][1], kf1, c);
                    s[mt][nt] = c;
                }
            }

            // ---- causal mask (diagonal-range tiles only) ----
#pragma unroll
            for (int mt = 0; mt < 2; ++mt) {
                if (k0 + 63 > q0w + mt * 16) {
#pragma unroll
                    for (int nt = 0; nt < 4; ++nt)
#pragma unroll
                        for (int r = 0; r < 4; ++r) {
                            int kg = k0 + nt * 16 + l15;
                            int qg = q0w + mt * 16 + lhi * 4 + r;
                            if (kg > qg) s[mt][nt][r] = -3.0e38f;
                        }
                }
            }

            // ---- online softmax (per mt: 4-level shfl over 16-lane group) ----
#pragma unroll
            for (int mt = 0; mt < 2; ++mt) {
                float tm[4], rs[4], alpha[4];
#pragma unroll
                for (int r = 0; r < 4; ++r)
                    tm[r] = fmaxf(fmaxf(s[mt][0][r], s[mt][1][r]),
                                  fmaxf(s[mt][2][r], s[mt][3][r]));
#pragma unroll
                for (int off = 8; off >= 1; off >>= 1)
#pragma unroll
                    for (int r = 0; r < 4; ++r)
                        tm[r] = fmaxf(tm[r], __shfl_xor(tm[r], off));
#pragma unroll
                for (int r = 0; r < 4; ++r) {
                    float mn = fmaxf(m_r[mt][r], tm[r]);
                    alpha[r] = exp2f(m_r[mt][r] - mn);
                    m_r[mt][r] = mn;
                    rs[r] = 0.f;
                }
#pragma unroll
                for (int nt = 0; nt < 4; ++nt)
#pragma unroll
                    for (int r = 0; r < 4; ++r) {
                        float pv = exp2f(s[mt][nt][r] - m_r[mt][r]);
                        s[mt][nt][r] = pv;
                        rs[r] += pv;
                    }
#pragma unroll
                for (int off = 8; off >= 1; off >>= 1)
#pragma unroll
                    for (int r = 0; r < 4; ++r) rs[r] += __shfl_xor(rs[r], off);
#pragma unroll
                for (int r = 0; r < 4; ++r)
                    l_r[mt][r] = l_r[mt][r] * alpha[r] + rs[r];
                // rescale O accumulators
#pragma unroll
                for (int d = 0; d < 4; ++d)
#pragma unroll
                    for (int r = 0; r < 4; ++r) oacc[mt][d][r] *= alpha[r];
                // P -> LDS (C-layout -> A-layout round trip), swizzled
#pragma unroll
                for (int nt = 0; nt < 4; ++nt)
#pragma unroll
                    for (int r = 0; r < 4; ++r)
                        Ps[wave][swze(mt * 16 + lhi * 4 + r, nt * 16 + l15)] =
                            __float2bfloat16(s[mt][nt][r]);
            }

            // ---- PV ----
#pragma unroll
            for (int kc = 0; kc < 2; ++kc) {
                bf16x8 vf[4];
#pragma unroll
                for (int dt = 0; dt < 4; ++dt)
                    vf[dt] = *(const bf16x8*)&Vt[p][swz8(dt * 16 + l15, kc * 4 + lhi)];
#pragma unroll
                for (int mt = 0; mt < 2; ++mt) {
                    bf16x8 pf =
                        *(const bf16x8*)&Ps[wave][swz8(mt * 16 + l15, kc * 4 + lhi)];
#pragma unroll
                    for (int dt = 0; dt < 4; ++dt)
                        oacc[mt][dt] = mfma16(pf, vf[dt], oacc[mt][dt]);
                }
            }
        }

        if (kt + 1 < NT) write_lds(p ^ 1);
        __syncthreads();
    }

#pragma unroll
    for (int mt = 0; mt < 2; ++mt)
#pragma unroll
        for (int dt = 0; dt < 4; ++dt)
#pragma unroll
            for (int r = 0; r < 4; ++r) {
                int qg = q0w + mt * 16 + lhi * 4 + r;
                int dg = dt * 16 + l15;
                float val = oacc[mt][dt][r] / l_r[mt][r];
                O[(size_t)qg * DMODEL + h * DK + dg] = __float2bfloat16(val);
            }
}

extern "C" void kernel_launch(void* const* d_in, const int* in_sizes, int n_in,
                              void* d_out, int out_size, void* d_ws, size_t ws_size,
                              hipStream_t stream) {
    const float* x  = (const float*)d_in[0];
    const float* Wq = (const float*)d_in[1];
    const float* Wk = (const float*)d_in[2];
    const float* Wv = (const float*)d_in[3];
    const float* Wo = (const float*)d_in[4];
    float* out = (float*)d_out;

    bf16* q_ws = (bf16*)d_ws;                    // [H][S][64] bf16
    bf16* k_ws = q_ws + (size_t)S_LEN * DMODEL;  // [H][S][64] bf16
    bf16* v_ws = k_ws + (size_t)S_LEN * DMODEL;  // [H][S][64] bf16
    bf16* a_ws = v_ws + (size_t)S_LEN * DMODEL;  // [S][D] bf16

    dim3 gq(DMODEL / 128, S_LEN / 128, 3);
    qkv_proj<<<gq, 256, 0, stream>>>(x, Wq, Wk, Wv, q_ws, k_ws, v_ws);
    dim3 ga(NHEAD, S_LEN / 128);
    attn_kernel<<<ga, 256, 0, stream>>>(q_ws, k_ws, v_ws, a_ws);
    dim3 go(DMODEL / 128, S_LEN / 128);
    out_proj<<<go, 256, 0, stream>>>(a_ws, Wo, out);
}

// Round 5
// 236.563 us; speedup vs baseline: 1.4433x; 1.1912x over previous
//
#include <hip/hip_runtime.h>
#include <hip/hip_bf16.h>

#define S_LEN 4096
#define DMODEL 1024
#define NHEAD 16
#define DK 64

typedef __hip_bfloat16 bf16;
typedef __attribute__((ext_vector_type(8))) __bf16 bf16x8;
typedef __attribute__((ext_vector_type(4))) float f32x4;

__device__ __forceinline__ f32x4 mfma16(bf16x8 a, bf16x8 b, f32x4 c) {
    return __builtin_amdgcn_mfma_f32_16x16x32_bf16(a, b, c, 0, 0, 0);
}

// async global->LDS, 16B per lane. LDS dest is wave-uniform base + lane*16.
__device__ __forceinline__ void async16(const bf16* g, bf16* l) {
    __builtin_amdgcn_global_load_lds(
        (const __attribute__((address_space(1))) unsigned int*)g,
        (__attribute__((address_space(3))) unsigned int*)l, 16, 0, 0);
}

__device__ __forceinline__ bf16x8 cvt8(float4 a, float4 b) {
    bf16x8 r;
    r[0] = (__bf16)a.x; r[1] = (__bf16)a.y; r[2] = (__bf16)a.z; r[3] = (__bf16)a.w;
    r[4] = (__bf16)b.x; r[5] = (__bf16)b.y; r[6] = (__bf16)b.z; r[7] = (__bf16)b.w;
    return r;
}

// XOR-swizzled index into a [rows][64] bf16 tile (128B rows): 16B slot ^ (row&7).
__device__ __forceinline__ int swze(int row, int col) {
    return row * 64 + ((((col >> 3) ^ (row & 7)) << 3) | (col & 7));
}
__device__ __forceinline__ int swz8(int row, int col8) {  // col8 = col>>3
    return row * 64 + ((col8 ^ (row & 7)) << 3);
}

// C[M=4096][N=1024] = A[M][K=1024] * B[N][K]^T, 128x128 tile, bf16 MFMA compute.
// MODE 0 (QKV): A = f32 global (convert-stage), out = bf16 head-major
// MODE 1 (OUT): A = bf16 ws (global_load_lds), out = f32 row-major
template <int MODE>
__device__ __forceinline__ void gemm_body(const void* Ap, const float* B,
                                          void* Cp, float scale) {
    constexpr int K = DMODEL;
    __shared__ bf16 As[128 * 32];
    __shared__ bf16 Bs[128 * 32];

    const int t = threadIdx.x;
    const int lane = t & 63;
    const int l15 = lane & 15, lhi = lane >> 4;
    const int wave = t >> 6;
    const int wm = wave >> 1, wn = wave & 1;
    const int bm = blockIdx.y, bn = blockIdx.x;

    const int srow = t >> 2, scol = (t & 3) * 8;

    const float* gB = B + (size_t)(bn * 128 + srow) * K + scol;
    const float* gAf = (const float*)Ap + (size_t)(bm * 128 + srow) * K + scol;
    const bf16* gAb = (const bf16*)Ap + (size_t)(bm * 128 + srow) * K + scol;

    f32x4 acc[4][4];
#pragma unroll
    for (int i = 0; i < 4; ++i)
#pragma unroll
        for (int j = 0; j < 4; ++j) acc[i][j] = (f32x4){0.f, 0.f, 0.f, 0.f};

    for (int kt = 0; kt < K / 32; ++kt) {
        if (MODE == 0) {
            float4 a0 = *(const float4*)(gAf + kt * 32);
            float4 a1 = *(const float4*)(gAf + kt * 32 + 4);
            *(bf16x8*)&As[srow * 32 + scol] = cvt8(a0, a1);
            float4 a2 = *(const float4*)(gAf + kt * 32 + 64 * K);
            float4 a3 = *(const float4*)(gAf + kt * 32 + 64 * K + 4);
            *(bf16x8*)&As[2048 + srow * 32 + scol] = cvt8(a2, a3);
        } else {
            async16(gAb + kt * 32,          (bf16*)As + t * 8);
            async16(gAb + kt * 32 + 64 * K, (bf16*)As + 2048 + t * 8);
        }
        {
            float4 b0 = *(const float4*)(gB + kt * 32);
            float4 b1 = *(const float4*)(gB + kt * 32 + 4);
            *(bf16x8*)&Bs[srow * 32 + scol] = cvt8(b0, b1);
            float4 b2 = *(const float4*)(gB + kt * 32 + 64 * K);
            float4 b3 = *(const float4*)(gB + kt * 32 + 64 * K + 4);
            *(bf16x8*)&Bs[2048 + srow * 32 + scol] = cvt8(b2, b3);
        }
        __syncthreads();

        bf16x8 af[4], bv[4];
#pragma unroll
        for (int mt = 0; mt < 4; ++mt)
            af[mt] = *(const bf16x8*)&As[(wm * 64 + mt * 16 + l15) * 32 + lhi * 8];
#pragma unroll
        for (int nt = 0; nt < 4; ++nt)
            bv[nt] = *(const bf16x8*)&Bs[(wn * 64 + nt * 16 + l15) * 32 + lhi * 8];
#pragma unroll
        for (int mt = 0; mt < 4; ++mt)
#pragma unroll
            for (int nt = 0; nt < 4; ++nt)
                acc[mt][nt] = mfma16(af[mt], bv[nt], acc[mt][nt]);
        __syncthreads();
    }

#pragma unroll
    for (int mt = 0; mt < 4; ++mt)
#pragma unroll
        for (int nt = 0; nt < 4; ++nt)
#pragma unroll
            for (int r = 0; r < 4; ++r) {
                int m = bm * 128 + wm * 64 + mt * 16 + lhi * 4 + r;
                int n = bn * 128 + wn * 64 + nt * 16 + l15;
                float v = acc[mt][nt][r] * scale;
                if (MODE == 0)
                    ((bf16*)Cp)[((size_t)(n >> 6) * S_LEN + m) * DK + (n & 63)] =
                        __float2bfloat16(v);
                else
                    ((float*)Cp)[(size_t)m * DMODEL + n] = v;
            }
}

__global__ __launch_bounds__(256) void qkv_proj(const float* __restrict__ x,
                                                const float* __restrict__ Wq,
                                                const float* __restrict__ Wk,
                                                const float* __restrict__ Wv,
                                                bf16* __restrict__ q,
                                                bf16* __restrict__ k,
                                                bf16* __restrict__ v) {
    const int z = blockIdx.z;
    const float* B = (z == 0) ? Wq : (z == 1 ? Wk : Wv);
    bf16* out = (z == 0) ? q : (z == 1 ? k : v);
    float scale = (z == 0) ? 0.18033688011112042f : 1.0f;  // (1/sqrt(64))*log2(e)
    gemm_body<0>(x, B, out, scale);
}

__global__ __launch_bounds__(256) void out_proj(const bf16* __restrict__ A,
                                                const float* __restrict__ Wo,
                                                float* __restrict__ C) {
    gemm_body<1>(A, Wo, C, 1.0f);
}

// Flash attention, causal. Block: 512 threads (8 waves x 16 q-rows = 128-row
// q-tile). Each block serially processes TWO (head, q-tile) units: unit b
// (long) then unit 511-b (short) -> uniform ~66 KV-steps per block (LPT
// pairing, no atomics). KV tile 64, double-buffered swizzled LDS, T14 split,
// T13 defer-max.
__global__ __launch_bounds__(512) void attn_kernel(const bf16* __restrict__ Q,
                                                   const bf16* __restrict__ Kg,
                                                   const bf16* __restrict__ Vg,
                                                   bf16* __restrict__ O) {
    __shared__ bf16 Ks[2][64 * 64];   // swizzled [kv][d]
    __shared__ bf16 Vt[2][64 * 64];   // swizzled [d][kv]
    __shared__ bf16 Ps[8][16 * 64];   // per-wave swizzled [qrow][kv]

    const int b = blockIdx.x;
    const int t = threadIdx.x;
    const int lane = t & 63;
    const int l15 = lane & 15, lhi = lane >> 4;
    const int wave = t >> 6;

    // staging assignments (512 threads)
    const int krow = t >> 3, kc8 = t & 7;          // K: row, 16B slot
    const int vrow = t >> 3, vd0 = (t & 7) * 8;    // V: kv row, 8 d-elems

    for (int ph = 0; ph < 2; ++ph) {
        const int u = (ph == 0) ? b : 511 - b;
        const int qb = 31 - (u >> 4);
        const int h = u & 15;

        const bf16* qh = Q + (size_t)h * S_LEN * DK;
        const bf16* kh = Kg + (size_t)h * S_LEN * DK;
        const bf16* vh = Vg + (size_t)h * S_LEN * DK;

        const int q0w = qb * 128 + wave * 16;

        bf16x8 qf0 = *(const bf16x8*)&qh[(size_t)(q0w + l15) * DK + lhi * 8];
        bf16x8 qf1 = *(const bf16x8*)&qh[(size_t)(q0w + l15) * DK + 32 + lhi * 8];

        float m_r[4], l_r[4];
        f32x4 oacc[4];
#pragma unroll
        for (int r = 0; r < 4; ++r) { m_r[r] = -3.0e38f; l_r[r] = 0.f; }
#pragma unroll
        for (int d = 0; d < 4; ++d) oacc[d] = (f32x4){0.f, 0.f, 0.f, 0.f};

        const int NT = 2 * qb + 2;
        uint4 kr, vr;

        auto load_regs = [&](int kt) {
            const int k0 = kt * 64;
            kr = *(const uint4*)&kh[(size_t)(k0 + krow) * DK + kc8 * 8];
            vr = *(const uint4*)&vh[(size_t)(k0 + vrow) * DK + vd0];
        };
        auto write_lds = [&](int buf) {
            *(uint4*)&Ks[buf][swz8(krow, kc8)] = kr;
            const bf16* pv = (const bf16*)&vr;
#pragma unroll
            for (int i = 0; i < 8; ++i) Vt[buf][swze(vd0 + i, vrow)] = pv[i];
        };

        load_regs(0);
        write_lds(0);
        __syncthreads();

        for (int kt = 0; kt < NT; ++kt) {
            const int k0 = kt * 64;
            const int p = kt & 1;
            if (kt + 1 < NT) load_regs(kt + 1);

            if (k0 <= q0w + 15) {  // causal skip for this wave's rows
                // ---- QK^T ----
                f32x4 s[4];
#pragma unroll
                for (int nt = 0; nt < 4; ++nt) {
                    const int krr = nt * 16 + l15;
                    bf16x8 kf0 = *(const bf16x8*)&Ks[p][swz8(krr, lhi)];
                    bf16x8 kf1 = *(const bf16x8*)&Ks[p][swz8(krr, 4 + lhi)];
                    f32x4 c = (f32x4){0.f, 0.f, 0.f, 0.f};
                    c = mfma16(qf0, kf0, c);
                    c = mfma16(qf1, kf1, c);
                    s[nt] = c;
                }

                // ---- causal mask (diagonal-range tiles) ----
                if (k0 + 63 > q0w) {
#pragma unroll
                    for (int nt = 0; nt < 4; ++nt)
#pragma unroll
                        for (int r = 0; r < 4; ++r) {
                            int kg = k0 + nt * 16 + l15;
                            int qg = q0w + lhi * 4 + r;
                            if (kg > qg) s[nt][r] = -3.0e38f;
                        }
                }

                // ---- online softmax with defer-max (T13) ----
                float tm[4], rs[4];
#pragma unroll
                for (int r = 0; r < 4; ++r)
                    tm[r] = fmaxf(fmaxf(s[0][r], s[1][r]), fmaxf(s[2][r], s[3][r]));
#pragma unroll
                for (int off = 8; off >= 1; off >>= 1)
#pragma unroll
                    for (int r = 0; r < 4; ++r)
                        tm[r] = fmaxf(tm[r], __shfl_xor(tm[r], off));

                float need = -3.0e38f;
#pragma unroll
                for (int r = 0; r < 4; ++r) need = fmaxf(need, tm[r] - m_r[r]);
                if (__any(need > 8.0f)) {  // max grew: rescale path
                    float alpha[4];
#pragma unroll
                    for (int r = 0; r < 4; ++r) {
                        float mn = fmaxf(m_r[r], tm[r]);
                        alpha[r] = exp2f(m_r[r] - mn);
                        m_r[r] = mn;
                        l_r[r] *= alpha[r];
                    }
#pragma unroll
                    for (int d = 0; d < 4; ++d)
#pragma unroll
                        for (int r = 0; r < 4; ++r) oacc[d][r] *= alpha[r];
                }
#pragma unroll
                for (int r = 0; r < 4; ++r) rs[r] = 0.f;
#pragma unroll
                for (int nt = 0; nt < 4; ++nt)
#pragma unroll
                    for (int r = 0; r < 4; ++r) {
                        float pv = exp2f(s[nt][r] - m_r[r]);  // log2e folded in Q
                        s[nt][r] = pv;
                        rs[r] += pv;
                    }
#pragma unroll
                for (int off = 8; off >= 1; off >>= 1)
#pragma unroll
                    for (int r = 0; r < 4; ++r) rs[r] += __shfl_xor(rs[r], off);
#pragma unroll
                for (int r = 0; r < 4; ++r) l_r[r] += rs[r];

                // P -> LDS (C-layout -> A-layout), swizzled
#pragma unroll
                for (int nt = 0; nt < 4; ++nt)
#pragma unroll
                    for (int r = 0; r < 4; ++r)
                        Ps[wave][swze(lhi * 4 + r, nt * 16 + l15)] =
                            __float2bfloat16(s[nt][r]);

                // ---- PV ----
#pragma unroll
                for (int kc = 0; kc < 2; ++kc) {
                    bf16x8 pf =
                        *(const bf16x8*)&Ps[wave][swz8(l15, kc * 4 + lhi)];
#pragma unroll
                    for (int dt = 0; dt < 4; ++dt) {
                        bf16x8 vf =
                            *(const bf16x8*)&Vt[p][swz8(dt * 16 + l15, kc * 4 + lhi)];
                        oacc[dt] = mfma16(pf, vf, oacc[dt]);
                    }
                }
            }

            if (kt + 1 < NT) write_lds(p ^ 1);
            __syncthreads();
        }

        // ---- output ----
#pragma unroll
        for (int dt = 0; dt < 4; ++dt)
#pragma unroll
            for (int r = 0; r < 4; ++r) {
                int qg = q0w + lhi * 4 + r;
                int dg = dt * 16 + l15;
                float val = oacc[dt][r] / l_r[r];
                O[(size_t)qg * DMODEL + h * DK + dg] = __float2bfloat16(val);
            }
        __syncthreads();  // all phase-1 LDS traffic done before phase-2 restage
    }
}

extern "C" void kernel_launch(void* const* d_in, const int* in_sizes, int n_in,
                              void* d_out, int out_size, void* d_ws, size_t ws_size,
                              hipStream_t stream) {
    const float* x  = (const float*)d_in[0];
    const float* Wq = (const float*)d_in[1];
    const float* Wk = (const float*)d_in[2];
    const float* Wv = (const float*)d_in[3];
    const float* Wo = (const float*)d_in[4];
    float* out = (float*)d_out;

    bf16* q_ws = (bf16*)d_ws;                    // [H][S][64] bf16
    bf16* k_ws = q_ws + (size_t)S_LEN * DMODEL;  // [H][S][64] bf16
    bf16* v_ws = k_ws + (size_t)S_LEN * DMODEL;  // [H][S][64] bf16
    bf16* a_ws = v_ws + (size_t)S_LEN * DMODEL;  // [S][D] bf16

    dim3 gq(DMODEL / 128, S_LEN / 128, 3);
    qkv_proj<<<gq, 256, 0, stream>>>(x, Wq, Wk, Wv, q_ws, k_ws, v_ws);
    attn_kernel<<<256, 512, 0, stream>>>(q_ws, k_ws, v_ws, a_ws);
    dim3 go(DMODEL / 128, S_LEN / 128);
    out_proj<<<go, 256, 0, stream>>>(a_ws, Wo, out);
}

// Round 6
// 201.959 us; speedup vs baseline: 1.6906x; 1.1713x over previous
//
#include <hip/hip_runtime.h>
#include <hip/hip_bf16.h>

#define S_LEN 4096
#define DMODEL 1024
#define NHEAD 16
#define DK 64

typedef __hip_bfloat16 bf16;
typedef __attribute__((ext_vector_type(8))) __bf16 bf16x8;
typedef __attribute__((ext_vector_type(4))) float f32x4;

__device__ __forceinline__ f32x4 mfma16(bf16x8 a, bf16x8 b, f32x4 c) {
    return __builtin_amdgcn_mfma_f32_16x16x32_bf16(a, b, c, 0, 0, 0);
}

// async global->LDS, 16B per lane. LDS dest is wave-uniform base + lane*16.
__device__ __forceinline__ void async16(const bf16* g, bf16* l) {
    __builtin_amdgcn_global_load_lds(
        (const __attribute__((address_space(1))) unsigned int*)g,
        (__attribute__((address_space(3))) unsigned int*)l, 16, 0, 0);
}

__device__ __forceinline__ bf16x8 cvt8(float4 a, float4 b) {
    bf16x8 r;
    r[0] = (__bf16)a.x; r[1] = (__bf16)a.y; r[2] = (__bf16)a.z; r[3] = (__bf16)a.w;
    r[4] = (__bf16)b.x; r[5] = (__bf16)b.y; r[6] = (__bf16)b.z; r[7] = (__bf16)b.w;
    return r;
}

// pack two f32 -> u32 of 2 bf16 (RNE); compiler emits cvt_pk
__device__ __forceinline__ unsigned int pkbf(float lo, float hi) {
    unsigned short a = __bfloat16_as_ushort(__float2bfloat16(lo));
    unsigned short b = __bfloat16_as_ushort(__float2bfloat16(hi));
    return (unsigned int)a | ((unsigned int)b << 16);
}

// XOR-swizzled index into a [rows][64] bf16 tile (128B rows): 16B slot ^ (row&7).
__device__ __forceinline__ int swze(int row, int col) {
    return row * 64 + ((((col >> 3) ^ (row & 7)) << 3) | (col & 7));
}
__device__ __forceinline__ int swz8(int row, int col8) {  // col8 = col>>3
    return row * 64 + ((col8 ^ (row & 7)) << 3);
}

// C[M=4096][N=1024] = A[M][K=1024] * B[N][K]^T, 128x128 tile, bf16 MFMA compute.
// MODE 0 (QKV): A = f32 global (convert-stage), out = bf16 head-major
// MODE 1 (OUT): A = bf16 ws (global_load_lds), out = f32 row-major
template <int MODE>
__device__ __forceinline__ void gemm_body(const void* Ap, const float* B,
                                          void* Cp, float scale) {
    constexpr int K = DMODEL;
    __shared__ bf16 As[128 * 32];
    __shared__ bf16 Bs[128 * 32];

    const int t = threadIdx.x;
    const int lane = t & 63;
    const int l15 = lane & 15, lhi = lane >> 4;
    const int wave = t >> 6;
    const int wm = wave >> 1, wn = wave & 1;
    const int bm = blockIdx.y, bn = blockIdx.x;

    const int srow = t >> 2, scol = (t & 3) * 8;

    const float* gB = B + (size_t)(bn * 128 + srow) * K + scol;
    const float* gAf = (const float*)Ap + (size_t)(bm * 128 + srow) * K + scol;
    const bf16* gAb = (const bf16*)Ap + (size_t)(bm * 128 + srow) * K + scol;

    f32x4 acc[4][4];
#pragma unroll
    for (int i = 0; i < 4; ++i)
#pragma unroll
        for (int j = 0; j < 4; ++j) acc[i][j] = (f32x4){0.f, 0.f, 0.f, 0.f};

    for (int kt = 0; kt < K / 32; ++kt) {
        if (MODE == 0) {
            float4 a0 = *(const float4*)(gAf + kt * 32);
            float4 a1 = *(const float4*)(gAf + kt * 32 + 4);
            *(bf16x8*)&As[srow * 32 + scol] = cvt8(a0, a1);
            float4 a2 = *(const float4*)(gAf + kt * 32 + 64 * K);
            float4 a3 = *(const float4*)(gAf + kt * 32 + 64 * K + 4);
            *(bf16x8*)&As[2048 + srow * 32 + scol] = cvt8(a2, a3);
        } else {
            async16(gAb + kt * 32,          (bf16*)As + t * 8);
            async16(gAb + kt * 32 + 64 * K, (bf16*)As + 2048 + t * 8);
        }
        {
            float4 b0 = *(const float4*)(gB + kt * 32);
            float4 b1 = *(const float4*)(gB + kt * 32 + 4);
            *(bf16x8*)&Bs[srow * 32 + scol] = cvt8(b0, b1);
            float4 b2 = *(const float4*)(gB + kt * 32 + 64 * K);
            float4 b3 = *(const float4*)(gB + kt * 32 + 64 * K + 4);
            *(bf16x8*)&Bs[2048 + srow * 32 + scol] = cvt8(b2, b3);
        }
        __syncthreads();

        bf16x8 af[4], bv[4];
#pragma unroll
        for (int mt = 0; mt < 4; ++mt)
            af[mt] = *(const bf16x8*)&As[(wm * 64 + mt * 16 + l15) * 32 + lhi * 8];
#pragma unroll
        for (int nt = 0; nt < 4; ++nt)
            bv[nt] = *(const bf16x8*)&Bs[(wn * 64 + nt * 16 + l15) * 32 + lhi * 8];
#pragma unroll
        for (int mt = 0; mt < 4; ++mt)
#pragma unroll
            for (int nt = 0; nt < 4; ++nt)
                acc[mt][nt] = mfma16(af[mt], bv[nt], acc[mt][nt]);
        __syncthreads();
    }

#pragma unroll
    for (int mt = 0; mt < 4; ++mt)
#pragma unroll
        for (int nt = 0; nt < 4; ++nt)
#pragma unroll
            for (int r = 0; r < 4; ++r) {
                int m = bm * 128 + wm * 64 + mt * 16 + lhi * 4 + r;
                int n = bn * 128 + wn * 64 + nt * 16 + l15;
                float v = acc[mt][nt][r] * scale;
                if (MODE == 0)
                    ((bf16*)Cp)[((size_t)(n >> 6) * S_LEN + m) * DK + (n & 63)] =
                        __float2bfloat16(v);
                else
                    ((float*)Cp)[(size_t)m * DMODEL + n] = v;
            }
}

__global__ __launch_bounds__(256) void qkv_proj(const float* __restrict__ x,
                                                const float* __restrict__ Wq,
                                                const float* __restrict__ Wk,
                                                const float* __restrict__ Wv,
                                                bf16* __restrict__ q,
                                                bf16* __restrict__ k,
                                                bf16* __restrict__ v) {
    const int z = blockIdx.z;
    const float* B = (z == 0) ? Wq : (z == 1 ? Wk : Wv);
    bf16* out = (z == 0) ? q : (z == 1 ? k : v);
    float scale = (z == 0) ? 0.18033688011112042f : 1.0f;  // (1/sqrt(64))*log2(e)
    gemm_body<0>(x, B, out, scale);
}

__global__ __launch_bounds__(256) void out_proj(const bf16* __restrict__ A,
                                                const float* __restrict__ Wo,
                                                float* __restrict__ C) {
    gemm_body<1>(A, Wo, C, 1.0f);
}

// Flash attention, causal. 512 threads = 8 waves x 16 q-rows (128-row q-tile).
// LPT pairing: block b does unit b (long) then 511-b (short), ~66 steps each.
// Swapped QK^T (mfma(K,Q)): lane holds full P-row for q=l15 -> scalar m/l,
// 2-shfl reductions, in-register P->bf16 + 16-shfl exchange to PV A-frags
// (no Ps LDS). K/V double-buffered swizzled LDS, T14 split, T13 defer-max.
__global__ __launch_bounds__(512) void attn_kernel(const bf16* __restrict__ Q,
                                                   const bf16* __restrict__ Kg,
                                                   const bf16* __restrict__ Vg,
                                                   bf16* __restrict__ O) {
    __shared__ bf16 Ks[2][64 * 64];   // swizzled [kv][d]
    __shared__ bf16 Vt[2][64 * 64];   // swizzled [d][kv]

    const int b = blockIdx.x;
    const int t = threadIdx.x;
    const int lane = t & 63;
    const int l15 = lane & 15, lhi = lane >> 4;
    const int wave = t >> 6;

    const int krow = t >> 3, kc8 = t & 7;  // K staging: row, 16B slot (octet-clean)

    for (int ph = 0; ph < 2; ++ph) {
        const int u = (ph == 0) ? b : 511 - b;
        const int qb = 31 - (u >> 4);
        const int h = u & 15;

        const bf16* qh = Q + (size_t)h * S_LEN * DK;
        const bf16* kh = Kg + (size_t)h * S_LEN * DK;
        const bf16* vh = Vg + (size_t)h * S_LEN * DK;

        const int q0w = qb * 128 + wave * 16;

        // Q B-fragments (B-frag layout == A-frag layout): row=q0w+l15, k chunks
        bf16x8 qf0 = *(const bf16x8*)&qh[(size_t)(q0w + l15) * DK + lhi * 8];
        bf16x8 qf1 = *(const bf16x8*)&qh[(size_t)(q0w + l15) * DK + 32 + lhi * 8];

        float m_s = -3.0e38f, l_s = 0.f;  // scalar state for q = q0w + l15
        f32x4 oacc[4];
#pragma unroll
        for (int d = 0; d < 4; ++d) oacc[d] = (f32x4){0.f, 0.f, 0.f, 0.f};

        const int NT = 2 * qb + 2;
        uint4 kr, vr;

        auto load_regs = [&](int kt) {
            const int k0 = kt * 64;
            kr = *(const uint4*)&kh[(size_t)(k0 + krow) * DK + kc8 * 8];
            // V: wave stages d-rows [8w,8w+8), lane = kv column
            vr = *(const uint4*)&vh[(size_t)(k0 + lane) * DK + wave * 8];
        };
        auto write_lds = [&](int buf) {
            *(uint4*)&Ks[buf][swz8(krow, kc8)] = kr;
            const bf16* pv = (const bf16*)&vr;
#pragma unroll
            for (int i = 0; i < 8; ++i) Vt[buf][swze(wave * 8 + i, lane)] = pv[i];
        };

        load_regs(0);
        write_lds(0);
        __syncthreads();

        for (int kt = 0; kt < NT; ++kt) {
            const int k0 = kt * 64;
            const int p = kt & 1;
            if (kt + 1 < NT) load_regs(kt + 1);

            if (k0 <= q0w + 15) {  // causal skip for this wave's rows
                // ---- swapped QK^T: s[nt][r] = score(q=q0w+l15, kv=k0+nt*16+lhi*4+r)
                f32x4 s[4];
#pragma unroll
                for (int nt = 0; nt < 4; ++nt) {
                    bf16x8 kf0 = *(const bf16x8*)&Ks[p][swz8(nt * 16 + l15, lhi)];
                    bf16x8 kf1 = *(const bf16x8*)&Ks[p][swz8(nt * 16 + l15, 4 + lhi)];
                    f32x4 c = (f32x4){0.f, 0.f, 0.f, 0.f};
                    c = mfma16(kf0, qf0, c);
                    c = mfma16(kf1, qf1, c);
                    s[nt] = c;
                }

                // ---- causal mask ----
                if (k0 + 63 > q0w) {
                    const int qg = q0w + l15;
#pragma unroll
                    for (int nt = 0; nt < 4; ++nt)
#pragma unroll
                        for (int r = 0; r < 4; ++r) {
                            int kg = k0 + nt * 16 + lhi * 4 + r;
                            if (kg > qg) s[nt][r] = -3.0e38f;
                        }
                }

                // ---- row max: 15 fmax + 2 shfl ----
                float tm = s[0][0];
#pragma unroll
                for (int nt = 0; nt < 4; ++nt)
#pragma unroll
                    for (int r = 0; r < 4; ++r) tm = fmaxf(tm, s[nt][r]);
                tm = fmaxf(tm, __shfl_xor(tm, 16));
                tm = fmaxf(tm, __shfl_xor(tm, 32));

                // ---- defer-max (T13) ----
                if (__any(tm - m_s > 8.0f)) {
                    float mn = fmaxf(m_s, tm);
                    float alpha = exp2f(m_s - mn);
                    m_s = mn;
                    l_s *= alpha;
                    float aR[4];
#pragma unroll
                    for (int r = 0; r < 4; ++r)
                        aR[r] = __shfl(alpha, (lane & 48) | (lhi * 4 + r));
#pragma unroll
                    for (int dt = 0; dt < 4; ++dt)
#pragma unroll
                        for (int r = 0; r < 4; ++r) oacc[dt][r] *= aR[r];
                }

                // ---- P = exp2(s - m), row sum ----
                float rs = 0.f;
#pragma unroll
                for (int nt = 0; nt < 4; ++nt)
#pragma unroll
                    for (int r = 0; r < 4; ++r) {
                        float pv = exp2f(s[nt][r] - m_s);  // log2e folded in Q
                        s[nt][r] = pv;
                        rs += pv;
                    }
                rs += __shfl_xor(rs, 16);
                rs += __shfl_xor(rs, 32);
                l_s += rs;

                // ---- pack P to bf16 pairs (r0|r1, r2|r3) ----
                unsigned int p32[4][2];
#pragma unroll
                for (int nt = 0; nt < 4; ++nt) {
                    p32[nt][0] = pkbf(s[nt][0], s[nt][1]);
                    p32[nt][1] = pkbf(s[nt][2], s[nt][3]);
                }

                // ---- PV: assemble A-frag via shfl exchange, mfma with Vt ----
                const int src0 = l15 | ((lhi & 1) << 5);  // lane 16*(2*(lhi&1)) + l15
                const int hsel = lhi >> 1;
#pragma unroll
                for (int kc = 0; kc < 2; ++kc) {
                    unsigned int w[4];
#pragma unroll
                    for (int c = 0; c < 2; ++c) {
                        int xa = __shfl((int)p32[2 * kc][c], src0);
                        int xb = __shfl((int)p32[2 * kc + 1][c], src0);
                        w[c] = (unsigned int)(hsel ? xb : xa);
                        int ya = __shfl((int)p32[2 * kc][c], src0 + 16);
                        int yb = __shfl((int)p32[2 * kc + 1][c], src0 + 16);
                        w[2 + c] = (unsigned int)(hsel ? yb : ya);
                    }
                    union { unsigned int u[4]; bf16x8 v; } pf;
                    pf.u[0] = w[0]; pf.u[1] = w[1]; pf.u[2] = w[2]; pf.u[3] = w[3];
#pragma unroll
                    for (int dt = 0; dt < 4; ++dt) {
                        bf16x8 vf =
                            *(const bf16x8*)&Vt[p][swz8(dt * 16 + l15, kc * 4 + lhi)];
                        oacc[dt] = mfma16(pf.v, vf, oacc[dt]);
                    }
                }
            }

            if (kt + 1 < NT) write_lds(p ^ 1);
            __syncthreads();
        }

        // ---- output: redistribute l to accumulator rows, store ----
        float lR[4];
#pragma unroll
        for (int r = 0; r < 4; ++r)
            lR[r] = __shfl(l_s, (lane & 48) | (lhi * 4 + r));
#pragma unroll
        for (int dt = 0; dt < 4; ++dt)
#pragma unroll
            for (int r = 0; r < 4; ++r) {
                int qg = q0w + lhi * 4 + r;
                int dg = dt * 16 + l15;
                float val = oacc[dt][r] / lR[r];
                O[(size_t)qg * DMODEL + h * DK + dg] = __float2bfloat16(val);
            }
        __syncthreads();  // phase-1 done before phase-2 restage
    }
}

extern "C" void kernel_launch(void* const* d_in, const int* in_sizes, int n_in,
                              void* d_out, int out_size, void* d_ws, size_t ws_size,
                              hipStream_t stream) {
    const float* x  = (const float*)d_in[0];
    const float* Wq = (const float*)d_in[1];
    const float* Wk = (const float*)d_in[2];
    const float* Wv = (const float*)d_in[3];
    const float* Wo = (const float*)d_in[4];
    float* out = (float*)d_out;

    bf16* q_ws = (bf16*)d_ws;                    // [H][S][64] bf16
    bf16* k_ws = q_ws + (size_t)S_LEN * DMODEL;  // [H][S][64] bf16
    bf16* v_ws = k_ws + (size_t)S_LEN * DMODEL;  // [H][S][64] bf16
    bf16* a_ws = v_ws + (size_t)S_LEN * DMODEL;  // [S][D] bf16

    dim3 gq(DMODEL / 128, S_LEN / 128, 3);
    qkv_proj<<<gq, 256, 0, stream>>>(x, Wq, Wk, Wv, q_ws, k_ws, v_ws);
    attn_kernel<<<256, 512, 0, stream>>>(q_ws, k_ws, v_ws, a_ws);
    dim3 go(DMODEL / 128, S_LEN / 128);
    out_proj<<<go, 256, 0, stream>>>(a_ws, Wo, out);
}